// Round 10
// baseline (458.117 us; speedup 1.0000x reference)
//
#include <hip/hip_runtime.h>

#define NUM_USER 100000
#define NUM_ITEM 50000
#define NNODE 150000
#define EMBED_DIM 64
#define NNZ_CNT 5000000
#define BATCH 4096

#define BROWS 256
#define NBUCK ((NNODE + BROWS - 1) / BROWS)       // 586
#define NBLK 512
#define CHUNK ((NNZ_CNT + NBLK - 1) / NBLK)       // 9766
#define COLMASK 0x3FFFF                            // 18 bits, col < 262144
#define RLSHIFT 18                                 // rl in bits 18..25
#define NSEG 5                                     // col segment = col >> 15 (4 MB bf16 each)
#define NBINS (BROWS * NSEG)                       // 1280
#define NBINS_PAD 1536                             // 512 threads * 3 bins

__device__ __forceinline__ unsigned short f2bf(float f) {
    unsigned b = __float_as_uint(f);
    return (unsigned short)((b + 0x7FFFu + ((b >> 16) & 1u)) >> 16);  // RNE
}
__device__ __forceinline__ float bf2f(unsigned short u) {
    return __uint_as_float((unsigned)u << 16);
}

// ---------- build: per-block hist -> 2-level scan -> scatter -> (row,seg) sort ----------

__global__ __launch_bounds__(1024) void bhist_local(const int* __restrict__ row,
                                                    int* __restrict__ histT) {
    __shared__ int lh[NBUCK];
    for (int i = threadIdx.x; i < NBUCK; i += blockDim.x) lh[i] = 0;
    __syncthreads();
    const int lo = blockIdx.x * CHUNK;
    const int hi = min(lo + CHUNK, NNZ_CNT);
    for (int e = lo + (int)threadIdx.x; e < hi; e += blockDim.x)
        atomicAdd(&lh[row[e] >> 8], 1);
    __syncthreads();
    for (int i = threadIdx.x; i < NBUCK; i += blockDim.x)
        histT[i * NBLK + blockIdx.x] = lh[i];
}

__global__ __launch_bounds__(512) void scanA(int* __restrict__ histT,
                                             int* __restrict__ btot) {
    const int g = (int)((blockIdx.x * blockDim.x + threadIdx.x) >> 6);
    const int lane = threadIdx.x & 63;
    if (g >= NBUCK) return;
    const int base = g * NBLK + lane * 8;
    int v[8];
    int s = 0;
    #pragma unroll
    for (int u = 0; u < 8; ++u) { v[u] = histT[base + u]; s += v[u]; }
    int pre = s;
    #pragma unroll
    for (int off = 1; off < 64; off <<= 1) {
        int t = __shfl_up(pre, off, 64);
        if (lane >= off) pre += t;
    }
    int excl = pre - s;
    #pragma unroll
    for (int u = 0; u < 8; ++u) { const int w = v[u]; histT[base + u] = excl; excl += w; }
    if (lane == 63) btot[g] = pre;
}

__global__ __launch_bounds__(1024) void scanB(const int* __restrict__ btot,
                                              int* __restrict__ bptr) {
    __shared__ int sums[1024];
    const int t = threadIdx.x;
    const int s = (t < NBUCK) ? btot[t] : 0;
    sums[t] = s;
    __syncthreads();
    for (int off = 1; off < 1024; off <<= 1) {
        int v = (t >= off) ? sums[t - off] : 0;
        __syncthreads();
        sums[t] += v;
        __syncthreads();
    }
    if (t < NBUCK) bptr[t] = sums[t] - s;
    if (t == 0) bptr[NBUCK] = NNZ_CNT;
}

__global__ __launch_bounds__(1024) void bscatter2(const float* __restrict__ vals,
                                                  const int* __restrict__ row,
                                                  const int* __restrict__ col,
                                                  const int* __restrict__ histT,
                                                  const int* __restrict__ bptr,
                                                  int2* __restrict__ grouped) {
    __shared__ int lh[NBUCK];
    const int b = blockIdx.x;
    for (int i = threadIdx.x; i < NBUCK; i += blockDim.x)
        lh[i] = bptr[i] + histT[i * NBLK + b];
    __syncthreads();
    const int lo = b * CHUNK;
    const int hi = min(lo + CHUNK, NNZ_CNT);
    for (int e = lo + (int)threadIdx.x; e < hi; e += blockDim.x) {
        const int r = row[e];
        const int bk = r >> 8;
        const int rl = r & 255;
        const int pos = atomicAdd(&lh[bk], 1);
        grouped[pos] = make_int2(col[e] | (rl << RLSHIFT), __float_as_int(vals[e]));
    }
}

// One WG per bucket: 1280-bin (row_local, col-seg) hist + parallel scan ->
// rsptr[(node)*NSEG + seg] offsets + CSR seg-ordered within each row.
__global__ __launch_bounds__(512) void bucket_sort(const int* __restrict__ bptr,
                                                   const int2* __restrict__ grouped,
                                                   int2* __restrict__ csr,
                                                   int* __restrict__ rsptr) {
    __shared__ int lh[NBINS_PAD];
    __shared__ int lbase[NBINS_PAD];
    __shared__ int wsum[8];
    const int tid = threadIdx.x;
    const int b = blockIdx.x;
    const int bstart = bptr[b];
    const int bend   = bptr[b + 1];
    for (int i = tid; i < NBINS_PAD; i += 512) lh[i] = 0;
    __syncthreads();
    for (int e = bstart + tid; e < bend; e += 512) {
        const unsigned cx = (unsigned)grouped[e].x;
        const int bin = (int)(cx >> RLSHIFT) * NSEG + (int)((cx & COLMASK) >> 15);
        atomicAdd(&lh[bin], 1);
    }
    __syncthreads();
    // block exclusive scan over NBINS_PAD bins, 3 bins per thread
    const int s0 = lh[tid * 3], s1 = lh[tid * 3 + 1], s2 = lh[tid * 3 + 2];
    const int s = s0 + s1 + s2;
    int pre = s;
    const int lane = tid & 63;
    #pragma unroll
    for (int off = 1; off < 64; off <<= 1) {
        int t = __shfl_up(pre, off, 64);
        if (lane >= off) pre += t;
    }
    if (lane == 63) wsum[tid >> 6] = pre;
    __syncthreads();
    if (tid == 0) {
        int run = 0;
        #pragma unroll
        for (int w = 0; w < 8; ++w) { const int v = wsum[w]; wsum[w] = run; run += v; }
    }
    __syncthreads();
    const int excl = pre - s + wsum[tid >> 6];
    lbase[tid * 3]     = excl;
    lbase[tid * 3 + 1] = excl + s0;
    lbase[tid * 3 + 2] = excl + s0 + s1;
    __syncthreads();
    // per-(row,seg) global offsets; global bin index = b*NBINS + i
    for (int i = tid; i < NBINS; i += 512)
        rsptr[b * NBINS + i] = bstart + lbase[i];
    // cursors
    for (int i = tid; i < NBINS_PAD; i += 512) lh[i] = lbase[i];
    __syncthreads();
    for (int e = bstart + tid; e < bend; e += 512) {
        const int2 rec = grouped[e];
        const unsigned cx = (unsigned)rec.x;
        const int bin = (int)(cx >> RLSHIFT) * NSEG + (int)((cx & COLMASK) >> 15);
        const int pos = bstart + atomicAdd(&lh[bin], 1);
        csr[pos] = make_int2((int)(cx & COLMASK), rec.y);
    }
}

// ---------- table concat -> bf16 ----------

__global__ void to_bf16(const float4* __restrict__ ut, const float4* __restrict__ it,
                        ushort4* __restrict__ xbf) {
    const int nu4 = NUM_USER * EMBED_DIM / 4;
    const int nt4 = NNODE * EMBED_DIM / 4;
    int i = blockIdx.x * blockDim.x + threadIdx.x;
    const int stride = gridDim.x * blockDim.x;
    for (; i < nt4; i += stride) {
        const float4 v = (i < nu4) ? ut[i] : it[i - nu4];
        ushort4 o;
        o.x = f2bf(v.x); o.y = f2bf(v.y); o.z = f2bf(v.z); o.w = f2bf(v.w);
        xbf[i] = o;
    }
}

// ---------- pull-mode SpMM (bf16 in / bf16 out), col-segmented ----------
// One wave per row, lane = channel. Per segment: 8-deep constant-offset
// scalar CSR reads + gathers restricted to a 4 MB x-slice (L2-resident);
// one masked clamped batch per segment (clamped line is L1-hot).

__global__ __launch_bounds__(256) void spmm_pull(const int* __restrict__ rsptr,
                          const int2* __restrict__ csr,
                          const unsigned short* __restrict__ x,
                          unsigned short* __restrict__ y) {
    const int wave = (int)((blockIdx.x * blockDim.x + threadIdx.x) >> 6);
    const int lane = threadIdx.x & 63;
    if (wave >= NNODE) return;
    const int rbase = wave * NSEG;
    int bnd[NSEG + 1];
    #pragma unroll
    for (int s = 0; s <= NSEG; ++s)
        bnd[s] = __builtin_amdgcn_readfirstlane(rsptr[rbase + s]);
    float acc = 0.f;
    #pragma unroll
    for (int s = 0; s < NSEG; ++s) {
        int j = bnd[s];
        const int je = bnd[s + 1];
        for (; j + 8 <= je; j += 8) {
            float vv[8], xv[8];
            #pragma unroll
            for (int u = 0; u < 8; ++u) {
                int2 rec; __builtin_memcpy(&rec, &csr[j + u], 8);  // s_load, const offset
                vv[u] = __int_as_float(rec.y);
                xv[u] = bf2f(x[(size_t)rec.x * EMBED_DIM + lane]);
            }
            #pragma unroll
            for (int u = 0; u < 8; ++u) acc += vv[u] * xv[u];
        }
        if (j < je) {                     // one masked batch per segment
            float vv[8], xv[8];
            #pragma unroll
            for (int u = 0; u < 8; ++u) {
                const int jj = j + u;
                const int idx = (jj < je) ? jj : je - 1;
                int2 rec; __builtin_memcpy(&rec, &csr[idx], 8);
                vv[u] = (jj < je) ? __int_as_float(rec.y) : 0.f;
                xv[u] = bf2f(x[(size_t)rec.x * EMBED_DIM + lane]);
            }
            #pragma unroll
            for (int u = 0; u < 8; ++u) acc += vv[u] * xv[u];
        }
    }
    y[(size_t)wave * EMBED_DIM + lane] = f2bf(acc);
}

// Layer-3 restricted pull for the 8192 batch rows only (whole-row bounds).
__global__ __launch_bounds__(256) void batch_pull(const int* __restrict__ rsptr,
                           const int2* __restrict__ csr,
                           const unsigned short* __restrict__ x,
                           const int* __restrict__ users,
                           const int* __restrict__ items,
                           float* __restrict__ uacc,
                           float* __restrict__ iacc) {
    const int g = (int)((blockIdx.x * blockDim.x + threadIdx.x) >> 6);
    const int lane = threadIdx.x & 63;
    if (g >= 2 * BATCH) return;
    const bool is_item = g >= BATCH;
    const int b = is_item ? g - BATCH : g;
    const int node = is_item ? items[b] + NUM_USER : users[b];
    const int start = __builtin_amdgcn_readfirstlane(rsptr[node * NSEG]);
    const int end   = __builtin_amdgcn_readfirstlane(rsptr[node * NSEG + NSEG]);
    float acc = 0.f;
    int j = start;
    for (; j + 16 <= end; j += 16) {
        float vv[16], xv[16];
        #pragma unroll
        for (int u = 0; u < 16; ++u) {
            int2 rec; __builtin_memcpy(&rec, &csr[j + u], 8);
            vv[u] = __int_as_float(rec.y);
            xv[u] = bf2f(x[(size_t)rec.x * EMBED_DIM + lane]);
        }
        #pragma unroll
        for (int u = 0; u < 16; ++u) acc += vv[u] * xv[u];
    }
    if (j < end) {
        float vv[16], xv[16];
        #pragma unroll
        for (int u = 0; u < 16; ++u) {
            const int jj = j + u;
            const int idx = (jj < end) ? jj : end - 1;
            int2 rec; __builtin_memcpy(&rec, &csr[idx], 8);
            vv[u] = (jj < end) ? __int_as_float(rec.y) : 0.f;
            xv[u] = bf2f(x[(size_t)rec.x * EMBED_DIM + lane]);
        }
        #pragma unroll
        for (int u = 0; u < 16; ++u) acc += vv[u] * xv[u];
    }
    float* dst = is_item ? iacc : uacc;
    dst[(size_t)b * EMBED_DIM + lane] += acc;
}

// ---------- accumulators / scoring ----------

__global__ void init_acc(const float* __restrict__ user_table,
                         const float* __restrict__ item_table,
                         const int* __restrict__ users,
                         const int* __restrict__ items,
                         float* __restrict__ uacc,
                         float* __restrict__ iacc) {
    const int tid = blockIdx.x * blockDim.x + threadIdx.x;
    const int b = tid >> 6;
    const int k = tid & 63;
    uacc[tid] = user_table[(size_t)users[b] * EMBED_DIM + k];
    iacc[tid] = item_table[(size_t)items[b] * EMBED_DIM + k];
}

__global__ void gather_add(const unsigned short* __restrict__ src,
                           const int* __restrict__ users,
                           const int* __restrict__ items,
                           float* __restrict__ uacc,
                           float* __restrict__ iacc) {
    const int tid = blockIdx.x * blockDim.x + threadIdx.x;
    const int b = tid >> 6;
    const int k = tid & 63;
    uacc[tid] += bf2f(src[(size_t)users[b] * EMBED_DIM + k]);
    iacc[tid] += bf2f(src[((size_t)items[b] + NUM_USER) * EMBED_DIM + k]);
}

__global__ void score_kernel(const float* __restrict__ uacc,
                             const float* __restrict__ iacc,
                             float* __restrict__ out) {
    const int tid = blockIdx.x * blockDim.x + threadIdx.x;
    const int b = tid >> 6;
    const int k = tid & 63;
    float p = uacc[tid] * iacc[tid];
    #pragma unroll
    for (int off = 32; off > 0; off >>= 1) p += __shfl_down(p, off, 64);
    if (k == 0) out[b] = p * (1.0f / 16.0f);
}

// ---------- launch ----------

extern "C" void kernel_launch(void* const* d_in, const int* in_sizes, int n_in,
                              void* d_out, int out_size, void* d_ws, size_t ws_size,
                              hipStream_t stream) {
    const float* vals       = (const float*)d_in[0];
    const float* user_table = (const float*)d_in[1];
    const float* item_table = (const float*)d_in[2];
    const int*   row        = (const int*)d_in[3];
    const int*   col        = (const int*)d_in[4];
    const int*   users      = (const int*)d_in[5];
    const int*   items      = (const int*)d_in[6];
    float* out = (float*)d_out;

    char* ws = (char*)d_ws;
    size_t off = 0;
    auto alloc = [&](size_t bytes) { char* p = ws + off; off += (bytes + 255) & ~(size_t)255; return p; };
    const size_t NBH = (size_t)NNODE * EMBED_DIM * sizeof(unsigned short); // 19.2 MB
    unsigned short* xbf  = (unsigned short*)alloc(NBH);
    unsigned short* bufA = (unsigned short*)alloc(NBH);
    int2*  grouped = (int2*)alloc((size_t)NNZ_CNT * sizeof(int2));   // 40 MB (bufB aliases)
    int2*  csr     = (int2*)alloc((size_t)NNZ_CNT * sizeof(int2));   // 40 MB
    int*   rsptr   = (int*)alloc(((size_t)NBUCK * NBINS + 1) * sizeof(int)); // 2.9 MB
    int*   bptr    = (int*)alloc((size_t)(NBUCK + 1) * sizeof(int));
    int*   btot    = (int*)alloc((size_t)NBUCK * sizeof(int));
    int*   histT   = (int*)alloc((size_t)NBUCK * NBLK * sizeof(int)); // 1.2 MB
    float* uacc    = (float*)alloc((size_t)BATCH * EMBED_DIM * sizeof(float));
    float* iacc    = (float*)alloc((size_t)BATCH * EMBED_DIM * sizeof(float));

    // build (seg-ordered CSR + per-(row,seg) offsets)
    bhist_local<<<NBLK, 1024, 0, stream>>>(row, histT);
    scanA<<<(NBUCK * 64 + 511) / 512, 512, 0, stream>>>(histT, btot);
    scanB<<<1, 1024, 0, stream>>>(btot, bptr);
    bscatter2<<<NBLK, 1024, 0, stream>>>(vals, row, col, histT, bptr, grouped);
    bucket_sort<<<NBUCK, 512, 0, stream>>>(bptr, grouped, csr, rsptr);

    // concat tables -> bf16
    to_bf16<<<2048, 256, 0, stream>>>((const float4*)user_table,
                                      (const float4*)item_table, (ushort4*)xbf);

    // hop 0
    init_acc<<<(BATCH * EMBED_DIM) / 256, 256, 0, stream>>>(user_table, item_table,
                                                            users, items, uacc, iacc);
    // hop 1 (full N)
    spmm_pull<<<(NNODE + 3) / 4, 256, 0, stream>>>(rsptr, csr, xbf, bufA);
    gather_add<<<(BATCH * EMBED_DIM) / 256, 256, 0, stream>>>(bufA, users, items, uacc, iacc);
    // hop 2 (full N); output aliases `grouped` (dead after bucket_sort)
    unsigned short* bufB = (unsigned short*)grouped;
    spmm_pull<<<(NNODE + 3) / 4, 256, 0, stream>>>(rsptr, csr, bufA, bufB);
    gather_add<<<(BATCH * EMBED_DIM) / 256, 256, 0, stream>>>(bufB, users, items, uacc, iacc);
    // hop 3 (restricted to the 8192 batch rows)
    batch_pull<<<(2 * BATCH * 64) / 256, 256, 0, stream>>>(rsptr, csr, bufB,
                                                           users, items, uacc, iacc);
    // scores
    score_kernel<<<(BATCH * EMBED_DIM) / 256, 256, 0, stream>>>(uacc, iacc, out);
}

// Round 11
// 297.928 us; speedup vs baseline: 1.5377x; 1.5377x over previous
//
#include <hip/hip_runtime.h>

#define NUM_USER 100000
#define NUM_ITEM 50000
#define NNODE 150000
#define EMBED_DIM 64
#define NNZ_CNT 5000000
#define BATCH 4096

#define BROWS 256
#define NBUCK ((NNODE + BROWS - 1) / BROWS)       // 586
#define NBLK 512
#define CHUNK ((NNZ_CNT + NBLK - 1) / NBLK)       // 9766
#define COLMASK 0x3FFFF                            // 18 bits, col < 262144
#define RLSHIFT 18                                 // rl in bits 18..25 of grouped.x
#define VSHIFT 18                                  // val14 in bits 18..31 of packed csr
#define VSCALE (1.0f / 16384.0f)

__device__ __forceinline__ unsigned short f2bf(float f) {
    unsigned b = __float_as_uint(f);
    return (unsigned short)((b + 0x7FFFu + ((b >> 16) & 1u)) >> 16);  // RNE
}
__device__ __forceinline__ float bf2f(unsigned short u) {
    return __uint_as_float((unsigned)u << 16);
}

// ---------- CSR build: per-block hist -> 2-level scan -> scatter -> bucket sort ----------

__global__ __launch_bounds__(1024) void bhist_local(const int* __restrict__ row,
                                                    int* __restrict__ histT) {
    __shared__ int lh[NBUCK];
    for (int i = threadIdx.x; i < NBUCK; i += blockDim.x) lh[i] = 0;
    __syncthreads();
    const int lo = blockIdx.x * CHUNK;
    const int hi = min(lo + CHUNK, NNZ_CNT);
    for (int e = lo + (int)threadIdx.x; e < hi; e += blockDim.x)
        atomicAdd(&lh[row[e] >> 8], 1);
    __syncthreads();
    for (int i = threadIdx.x; i < NBUCK; i += blockDim.x)
        histT[i * NBLK + blockIdx.x] = lh[i];
}

__global__ __launch_bounds__(512) void scanA(int* __restrict__ histT,
                                             int* __restrict__ btot) {
    const int g = (int)((blockIdx.x * blockDim.x + threadIdx.x) >> 6);
    const int lane = threadIdx.x & 63;
    if (g >= NBUCK) return;
    const int base = g * NBLK + lane * 8;
    int v[8];
    int s = 0;
    #pragma unroll
    for (int u = 0; u < 8; ++u) { v[u] = histT[base + u]; s += v[u]; }
    int pre = s;
    #pragma unroll
    for (int off = 1; off < 64; off <<= 1) {
        int t = __shfl_up(pre, off, 64);
        if (lane >= off) pre += t;
    }
    int excl = pre - s;
    #pragma unroll
    for (int u = 0; u < 8; ++u) { const int w = v[u]; histT[base + u] = excl; excl += w; }
    if (lane == 63) btot[g] = pre;
}

__global__ __launch_bounds__(1024) void scanB(const int* __restrict__ btot,
                                              int* __restrict__ bptr) {
    __shared__ int sums[1024];
    const int t = threadIdx.x;
    const int s = (t < NBUCK) ? btot[t] : 0;
    sums[t] = s;
    __syncthreads();
    for (int off = 1; off < 1024; off <<= 1) {
        int v = (t >= off) ? sums[t - off] : 0;
        __syncthreads();
        sums[t] += v;
        __syncthreads();
    }
    if (t < NBUCK) bptr[t] = sums[t] - s;
    if (t == 0) bptr[NBUCK] = NNZ_CNT;
}

__global__ __launch_bounds__(1024) void bscatter2(const float* __restrict__ vals,
                                                  const int* __restrict__ row,
                                                  const int* __restrict__ col,
                                                  const int* __restrict__ histT,
                                                  const int* __restrict__ bptr,
                                                  int2* __restrict__ grouped) {
    __shared__ int lh[NBUCK];
    const int b = blockIdx.x;
    for (int i = threadIdx.x; i < NBUCK; i += blockDim.x)
        lh[i] = bptr[i] + histT[i * NBLK + b];
    __syncthreads();
    const int lo = b * CHUNK;
    const int hi = min(lo + CHUNK, NNZ_CNT);
    for (int e = lo + (int)threadIdx.x; e < hi; e += blockDim.x) {
        const int r = row[e];
        const int bk = r >> 8;
        const int rl = r & 255;
        const int pos = atomicAdd(&lh[bk], 1);
        grouped[pos] = make_int2(col[e] | (rl << RLSHIFT), __float_as_int(vals[e]));
    }
}

// One WG per bucket: LDS 256-bin hist + scan -> row_ptr + contiguous PACKED csr.
// Packed entry: val14 << 18 | col18   (val = u/16384, u in [0,16383])
__global__ __launch_bounds__(512) void bucket_sort(const int* __restrict__ bptr,
                                                   const int2* __restrict__ grouped,
                                                   unsigned* __restrict__ csr,
                                                   int* __restrict__ row_ptr) {
    __shared__ int lh[BROWS];
    __shared__ int lbase[BROWS];
    const int b = blockIdx.x;
    const int bstart = bptr[b];
    const int bend   = bptr[b + 1];
    if (threadIdx.x < BROWS) lh[threadIdx.x] = 0;
    __syncthreads();
    for (int e = bstart + (int)threadIdx.x; e < bend; e += blockDim.x)
        atomicAdd(&lh[((unsigned)grouped[e].x) >> RLSHIFT], 1);
    __syncthreads();
    if (threadIdx.x == 0) {
        int run = 0;
        for (int i = 0; i < BROWS; ++i) { const int c = lh[i]; lbase[i] = run; run += c; }
    }
    __syncthreads();
    const int node = b * BROWS + (int)threadIdx.x;
    if (threadIdx.x < BROWS && node < NNODE) row_ptr[node] = bstart + lbase[threadIdx.x];
    if (threadIdx.x < BROWS) lh[threadIdx.x] = lbase[threadIdx.x];
    __syncthreads();
    for (int e = bstart + (int)threadIdx.x; e < bend; e += blockDim.x) {
        const int2 rec = grouped[e];
        const int rl = ((unsigned)rec.x) >> RLSHIFT;
        const int pos = bstart + atomicAdd(&lh[rl], 1);
        unsigned u = (unsigned)(__int_as_float(rec.y) * 16384.0f + 0.5f);
        if (u > 16383u) u = 16383u;
        csr[pos] = (u << VSHIFT) | ((unsigned)rec.x & COLMASK);
    }
}

__global__ void fix_tail(int* __restrict__ row_ptr) {
    row_ptr[NNODE] = NNZ_CNT;
}

// ---------- table concat -> bf16 ----------

__global__ void to_bf16(const float4* __restrict__ ut, const float4* __restrict__ it,
                        ushort4* __restrict__ xbf) {
    const int nu4 = NUM_USER * EMBED_DIM / 4;
    const int nt4 = NNODE * EMBED_DIM / 4;
    int i = blockIdx.x * blockDim.x + threadIdx.x;
    const int stride = gridDim.x * blockDim.x;
    for (; i < nt4; i += stride) {
        const float4 v = (i < nu4) ? ut[i] : it[i - nu4];
        ushort4 o;
        o.x = f2bf(v.x); o.y = f2bf(v.y); o.z = f2bf(v.z); o.w = f2bf(v.w);
        xbf[i] = o;
    }
}

// ---------- pull-mode SpMM (bf16 in / bf16 out), packed 4B CSR ----------
// One wave per row, lane = channel. Edge stream: wave-uniform scalar loads at
// constant offsets (merged s_load_dwordx8); 16 gathers in flight. Tail:
// masked-8 or masked-16 (wave-uniform branch), vals zeroed on waste slots.
// val = (packed>>18)/16384; the /16384 factors out of the row sum.

__global__ __launch_bounds__(256) void spmm_pull(const int* __restrict__ row_ptr,
                          const unsigned* __restrict__ csr,
                          const unsigned short* __restrict__ x,
                          unsigned short* __restrict__ y) {
    const int wave = (int)((blockIdx.x * blockDim.x + threadIdx.x) >> 6);
    const int lane = threadIdx.x & 63;
    if (wave >= NNODE) return;
    const int start = __builtin_amdgcn_readfirstlane(row_ptr[wave]);
    const int end   = __builtin_amdgcn_readfirstlane(row_ptr[wave + 1]);
    float acc = 0.f;
    int j = start;
    for (; j + 16 <= end; j += 16) {
        unsigned ee[16]; float xv[16];
        #pragma unroll
        for (int u = 0; u < 16; ++u) {
            __builtin_memcpy(&ee[u], &csr[j + u], 4);            // s_load, const offset
            xv[u] = bf2f(x[(size_t)(ee[u] & COLMASK) * EMBED_DIM + lane]);
        }
        #pragma unroll
        for (int u = 0; u < 16; ++u) acc += (float)(ee[u] >> VSHIFT) * xv[u];
    }
    const int rem = end - j;
    if (rem > 8) {                                 // masked-16 (wave-uniform branch)
        float vv[16], xv[16];
        #pragma unroll
        for (int u = 0; u < 16; ++u) {
            const int jj = j + u;
            const int idx = (jj < end) ? jj : end - 1;
            unsigned e; __builtin_memcpy(&e, &csr[idx], 4);
            vv[u] = (jj < end) ? (float)(e >> VSHIFT) : 0.f;
            xv[u] = bf2f(x[(size_t)(e & COLMASK) * EMBED_DIM + lane]);
        }
        #pragma unroll
        for (int u = 0; u < 16; ++u) acc += vv[u] * xv[u];
    } else if (rem > 0) {                          // masked-8
        float vv[8], xv[8];
        #pragma unroll
        for (int u = 0; u < 8; ++u) {
            const int jj = j + u;
            const int idx = (jj < end) ? jj : end - 1;
            unsigned e; __builtin_memcpy(&e, &csr[idx], 4);
            vv[u] = (jj < end) ? (float)(e >> VSHIFT) : 0.f;
            xv[u] = bf2f(x[(size_t)(e & COLMASK) * EMBED_DIM + lane]);
        }
        #pragma unroll
        for (int u = 0; u < 8; ++u) acc += vv[u] * xv[u];
    }
    y[(size_t)wave * EMBED_DIM + lane] = f2bf(acc * VSCALE);
}

// Layer-3 restricted pull for the 8192 batch rows only (same pattern).
__global__ __launch_bounds__(256) void batch_pull(const int* __restrict__ row_ptr,
                           const unsigned* __restrict__ csr,
                           const unsigned short* __restrict__ x,
                           const int* __restrict__ users,
                           const int* __restrict__ items,
                           float* __restrict__ uacc,
                           float* __restrict__ iacc) {
    const int g = (int)((blockIdx.x * blockDim.x + threadIdx.x) >> 6);
    const int lane = threadIdx.x & 63;
    if (g >= 2 * BATCH) return;
    const bool is_item = g >= BATCH;
    const int b = is_item ? g - BATCH : g;
    const int node = is_item ? items[b] + NUM_USER : users[b];
    const int start = __builtin_amdgcn_readfirstlane(row_ptr[node]);
    const int end   = __builtin_amdgcn_readfirstlane(row_ptr[node + 1]);
    float acc = 0.f;
    int j = start;
    for (; j + 16 <= end; j += 16) {
        unsigned ee[16]; float xv[16];
        #pragma unroll
        for (int u = 0; u < 16; ++u) {
            __builtin_memcpy(&ee[u], &csr[j + u], 4);
            xv[u] = bf2f(x[(size_t)(ee[u] & COLMASK) * EMBED_DIM + lane]);
        }
        #pragma unroll
        for (int u = 0; u < 16; ++u) acc += (float)(ee[u] >> VSHIFT) * xv[u];
    }
    const int rem = end - j;
    if (rem > 8) {
        float vv[16], xv[16];
        #pragma unroll
        for (int u = 0; u < 16; ++u) {
            const int jj = j + u;
            const int idx = (jj < end) ? jj : end - 1;
            unsigned e; __builtin_memcpy(&e, &csr[idx], 4);
            vv[u] = (jj < end) ? (float)(e >> VSHIFT) : 0.f;
            xv[u] = bf2f(x[(size_t)(e & COLMASK) * EMBED_DIM + lane]);
        }
        #pragma unroll
        for (int u = 0; u < 16; ++u) acc += vv[u] * xv[u];
    } else if (rem > 0) {
        float vv[8], xv[8];
        #pragma unroll
        for (int u = 0; u < 8; ++u) {
            const int jj = j + u;
            const int idx = (jj < end) ? jj : end - 1;
            unsigned e; __builtin_memcpy(&e, &csr[idx], 4);
            vv[u] = (jj < end) ? (float)(e >> VSHIFT) : 0.f;
            xv[u] = bf2f(x[(size_t)(e & COLMASK) * EMBED_DIM + lane]);
        }
        #pragma unroll
        for (int u = 0; u < 8; ++u) acc += vv[u] * xv[u];
    }
    float* dst = is_item ? iacc : uacc;
    dst[(size_t)b * EMBED_DIM + lane] += acc * VSCALE;
}

// ---------- accumulators / scoring ----------

__global__ void init_acc(const float* __restrict__ user_table,
                         const float* __restrict__ item_table,
                         const int* __restrict__ users,
                         const int* __restrict__ items,
                         float* __restrict__ uacc,
                         float* __restrict__ iacc) {
    const int tid = blockIdx.x * blockDim.x + threadIdx.x;
    const int b = tid >> 6;
    const int k = tid & 63;
    uacc[tid] = user_table[(size_t)users[b] * EMBED_DIM + k];
    iacc[tid] = item_table[(size_t)items[b] * EMBED_DIM + k];
}

__global__ void gather_add(const unsigned short* __restrict__ src,
                           const int* __restrict__ users,
                           const int* __restrict__ items,
                           float* __restrict__ uacc,
                           float* __restrict__ iacc) {
    const int tid = blockIdx.x * blockDim.x + threadIdx.x;
    const int b = tid >> 6;
    const int k = tid & 63;
    uacc[tid] += bf2f(src[(size_t)users[b] * EMBED_DIM + k]);
    iacc[tid] += bf2f(src[((size_t)items[b] + NUM_USER) * EMBED_DIM + k]);
}

__global__ void score_kernel(const float* __restrict__ uacc,
                             const float* __restrict__ iacc,
                             float* __restrict__ out) {
    const int tid = blockIdx.x * blockDim.x + threadIdx.x;
    const int b = tid >> 6;
    const int k = tid & 63;
    float p = uacc[tid] * iacc[tid];
    #pragma unroll
    for (int off = 32; off > 0; off >>= 1) p += __shfl_down(p, off, 64);
    if (k == 0) out[b] = p * (1.0f / 16.0f);
}

// ---------- launch ----------

extern "C" void kernel_launch(void* const* d_in, const int* in_sizes, int n_in,
                              void* d_out, int out_size, void* d_ws, size_t ws_size,
                              hipStream_t stream) {
    const float* vals       = (const float*)d_in[0];
    const float* user_table = (const float*)d_in[1];
    const float* item_table = (const float*)d_in[2];
    const int*   row        = (const int*)d_in[3];
    const int*   col        = (const int*)d_in[4];
    const int*   users      = (const int*)d_in[5];
    const int*   items      = (const int*)d_in[6];
    float* out = (float*)d_out;

    char* ws = (char*)d_ws;
    size_t off = 0;
    auto alloc = [&](size_t bytes) { char* p = ws + off; off += (bytes + 255) & ~(size_t)255; return p; };
    const size_t NBH = (size_t)NNODE * EMBED_DIM * sizeof(unsigned short); // 19.2 MB
    unsigned short* xbf  = (unsigned short*)alloc(NBH);
    unsigned short* bufA = (unsigned short*)alloc(NBH);
    int2*  grouped = (int2*)alloc((size_t)NNZ_CNT * sizeof(int2));      // 40 MB (bufB aliases)
    unsigned* csr  = (unsigned*)alloc((size_t)NNZ_CNT * sizeof(unsigned)); // 20 MB packed
    int*   row_ptr = (int*)alloc((size_t)(NNODE + 1) * sizeof(int));
    int*   bptr    = (int*)alloc((size_t)(NBUCK + 1) * sizeof(int));
    int*   btot    = (int*)alloc((size_t)NBUCK * sizeof(int));
    int*   histT   = (int*)alloc((size_t)NBUCK * NBLK * sizeof(int));   // 1.2 MB
    float* uacc    = (float*)alloc((size_t)BATCH * EMBED_DIM * sizeof(float));
    float* iacc    = (float*)alloc((size_t)BATCH * EMBED_DIM * sizeof(float));

    // CSR build
    bhist_local<<<NBLK, 1024, 0, stream>>>(row, histT);
    scanA<<<(NBUCK * 64 + 511) / 512, 512, 0, stream>>>(histT, btot);
    scanB<<<1, 1024, 0, stream>>>(btot, bptr);
    bscatter2<<<NBLK, 1024, 0, stream>>>(vals, row, col, histT, bptr, grouped);
    bucket_sort<<<NBUCK, 512, 0, stream>>>(bptr, grouped, csr, row_ptr);
    fix_tail<<<1, 1, 0, stream>>>(row_ptr);

    // concat tables -> bf16
    to_bf16<<<2048, 256, 0, stream>>>((const float4*)user_table,
                                      (const float4*)item_table, (ushort4*)xbf);

    // hop 0
    init_acc<<<(BATCH * EMBED_DIM) / 256, 256, 0, stream>>>(user_table, item_table,
                                                            users, items, uacc, iacc);
    // hop 1 (full N)
    spmm_pull<<<(NNODE + 3) / 4, 256, 0, stream>>>(row_ptr, csr, xbf, bufA);
    gather_add<<<(BATCH * EMBED_DIM) / 256, 256, 0, stream>>>(bufA, users, items, uacc, iacc);
    // hop 2 (full N); output aliases `grouped` (dead after bucket_sort)
    unsigned short* bufB = (unsigned short*)grouped;
    spmm_pull<<<(NNODE + 3) / 4, 256, 0, stream>>>(row_ptr, csr, bufA, bufB);
    gather_add<<<(BATCH * EMBED_DIM) / 256, 256, 0, stream>>>(bufB, users, items, uacc, iacc);
    // hop 3 (restricted to the 8192 batch rows)
    batch_pull<<<(2 * BATCH * 64) / 256, 256, 0, stream>>>(row_ptr, csr, bufB,
                                                           users, items, uacc, iacc);
    // scores
    score_kernel<<<(BATCH * EMBED_DIM) / 256, 256, 0, stream>>>(uacc, iacc, out);
}